// Round 10
// baseline (253.999 us; speedup 1.0000x reference)
//
#include <hip/hip_runtime.h>
#include <math.h>

#define BATCH 64
#define NN 512
#define MM 512
#define DD 128
#define BIGF 1e30f
#define KLOG2E 1.442695040888963f
#define LN2F   0.693147180559945f
#define BIGK   (BIGF * KLOG2E)

typedef __attribute__((ext_vector_type(2))) float f32x2;
typedef __attribute__((ext_vector_type(4))) float f32x4;

// ---------------------------------------------------------------------------
// Kernel 1: squared row norms of X (B*N rows) and Y (B*M rows).
// ---------------------------------------------------------------------------
__global__ __launch_bounds__(256) void sqnorm_kernel(const float* __restrict__ X,
                                                     const float* __restrict__ Y,
                                                     float* __restrict__ x2,
                                                     float* __restrict__ y2) {
    int row  = blockIdx.x * 4 + (threadIdx.x >> 6);
    int lane = threadIdx.x & 63;
    const float* src;
    float* dst;
    int r;
    if (row < BATCH * NN) { src = X; dst = x2; r = row; }
    else                  { src = Y; dst = y2; r = row - BATCH * NN; }
    const float* p = src + (size_t)r * DD;
    float a = p[lane];
    float b = p[lane + 64];
    float s = a * a + b * b;
    #pragma unroll
    for (int m = 32; m >= 1; m >>= 1) s += __shfl_xor(s, m, 64);
    if (lane == 0) dst[r] = s;
}

// ---------------------------------------------------------------------------
// Kernel 2: CT[b,j,i] = (x2[b,i] + y2[b,j] - 2*dot(X,Y)) * (log2e / D)
// Pre-scaled by log2(e): DTW kernel runs natively in base-2 domain.
// ---------------------------------------------------------------------------
#define TM 64

__global__ __launch_bounds__(256) void cost_kernel(const float* __restrict__ X,
                                                   const float* __restrict__ Y,
                                                   const float* __restrict__ x2,
                                                   const float* __restrict__ y2,
                                                   float* __restrict__ CT) {
    __shared__ float Xs[TM * DD];
    __shared__ float Ys[TM * DD];
    int b  = blockIdx.z;
    int ti = blockIdx.y * TM;
    int tj = blockIdx.x * TM;
    int t  = threadIdx.x;
    const float* Xb = X + ((size_t)b * NN + ti) * DD;
    const float* Yb = Y + ((size_t)b * MM + tj) * DD;

    int k4l = t & 31;
    int rl  = t >> 5;
    #pragma unroll
    for (int it = 0; it < 8; ++it) {
        int r  = rl + it * 8;
        int sw = r * 32 + (k4l ^ ((r >> 2) & 7));
        *(float4*)&Xs[4 * sw] = *(const float4*)&Xb[(size_t)r * DD + 4 * k4l];
        *(float4*)&Ys[4 * sw] = *(const float4*)&Yb[(size_t)r * DD + 4 * k4l];
    }
    __syncthreads();

    int tx = t & 15;
    int ty = t >> 4;
    float acc[4][4] = {};
    #pragma unroll 4
    for (int k4 = 0; k4 < 32; ++k4) {
        float4 xa[4], yb[4];
        int kx = k4 ^ (tx & 7);
        int ky = k4 ^ ty;
        #pragma unroll
        for (int m = 0; m < 4; ++m)
            xa[m] = *(const float4*)&Xs[4 * ((tx * 4 + m) * 32 + kx)];
        #pragma unroll
        for (int n = 0; n < 4; ++n)
            yb[n] = *(const float4*)&Ys[4 * ((ty * 4 + n) * 32 + ky)];
        #pragma unroll
        for (int m = 0; m < 4; ++m)
            #pragma unroll
            for (int n = 0; n < 4; ++n)
                acc[m][n] += xa[m].x * yb[n].x + xa[m].y * yb[n].y
                           + xa[m].z * yb[n].z + xa[m].w * yb[n].w;
    }

    const float inv = KLOG2E / (float)DD;
    int i0 = ti + tx * 4;
    float4 xx = *(const float4*)&x2[b * NN + i0];
    #pragma unroll
    for (int n = 0; n < 4; ++n) {
        int j = tj + ty * 4 + n;
        float yy = y2[b * MM + j];
        float4 o;
        o.x = (xx.x + yy - 2.0f * acc[0][n]) * inv;
        o.y = (xx.y + yy - 2.0f * acc[1][n]) * inv;
        o.z = (xx.z + yy - 2.0f * acc[2][n]) * inv;
        o.w = (xx.w + yy - 2.0f * acc[3][n]) * inv;
        *(float4*)&CT[((size_t)b * MM + j) * NN + i0] = o;
    }
}

// ---------------------------------------------------------------------------
// Kernel 3: 4-wave soft-DTW, (s,q) carry, K=16 chunks, REGISTER boundary ring.
// vs r9: the per-step LDS write (producer) and read (consumer prefetch) are
// replaced by named registers; LDS is touched only ONCE per 16-step chunk
// (lane63 bulk-writes 16 pairs; all lanes bulk-read 8 x b128 broadcast).
// Per-step DS ops = the 2 shfl bpermutes ONLY, so the compiler's lgkmcnt(0)
// before consuming the shfl has nothing else to drain (issued a full ~250cyc
// step earlier -> ~free). One raw s_barrier per chunk, double-buffered LDS:
// write buf[I&1] at end of iter I, read buf[(I+1)&1] at top (stable since
// end of iter I-1, which is before barrier I).
// ---------------------------------------------------------------------------
#define RING 8
#define KCH 16
#define ESK 15
#define NITER 51   // 816 steps >= 512 + 255 + 45 + 1

__global__ __launch_bounds__(256) void sdtw_kernel(const float* __restrict__ CT,
                                                   float* __restrict__ part) {
    int b = blockIdx.x;
    int p = threadIdx.x;          // 0..255
    int l = p & 63;
    int w = p >> 6;
    int wm1 = (w == 0) ? 0 : (w - 1);
    int off = p + ESK * w;        // column skew: j = s - off
    const char* CbL = (const char*)CT + (size_t)b * (MM * NN * 4) + p * 8;

    __shared__ alignas(16) f32x2 buf[2][4][KCH];   // [parity][wave][slot], 1 KB

    if (p < 128) ((f32x2*)buf)[p] = f32x2{BIGK, 1.0f};
    __syncthreads();

    float ps0 = BIGK, pq0 = 1.0f;      // row 2p   pair at col j-1
    float ps1 = BIGK, pq1 = 1.0f;      // row 2p+1 pair at col j-1
    float nbc_s = BIGK, nbc_q = 1.0f;  // shfl up-pair   (lanes 1..63)
    float nbp_s = BIGK, nbp_q = 1.0f;  // shfl diag-pair (lanes 1..63)
    f32x2 carry = {BIGK, 1.0f};        // consumer pair 15 of previous chunk

    // producer boundary ring (this thread's bottom pairs; only lane63's used)
    f32x2 b0, b1, b2, b3, b4, b5, b6, b7, b8, b9, b10, b11, b12, b13, b14, b15;
    b0=b1=b2=b3=b4=b5=b6=b7=b8=b9=b10=b11=b12=b13=b14=b15 = f32x2{BIGK, 1.0f};

    f32x2 r0, r1, r2, r3, r4, r5, r6, r7;

#define LOADP(REG, COL) do {                                                   \
    const char* pa_ = CbL + (((unsigned)(COL)) & 511u) * 2048u;                \
    asm volatile("global_load_dwordx2 %0, %1, off"                             \
                 : "=&v"(REG) : "v"(pa_) : "memory");                          \
} while (0)

    LOADP(r0, 0 - off); LOADP(r1, 1 - off); LOADP(r2, 2 - off);
    LOADP(r3, 3 - off); LOADP(r4, 4 - off); LOADP(r5, 5 - off);
    LOADP(r6, 6 - off); LOADP(r7, 7 - off);

#define STEP(REG, SIG, BS, UBX, UBY, DBX, DBY) do {                            \
    int s_ = sbase + (SIG);                                                    \
    int j_ = s_ - off;                                                         \
    asm volatile("s_waitcnt vmcnt(7)" ::: "memory");                           \
    __builtin_amdgcn_sched_barrier(0);                                         \
    f32x2 cc = REG;                                                            \
    float su, qu, sd2, qd;                                                     \
    if (l == 0) {                                                              \
        if (w == 0) { su = BIGK; qu = 1.0f;                                    \
                      sd2 = (s_ == 0) ? 0.0f : BIGK; qd = 1.0f; }              \
        else        { su = (UBX); qu = (UBY); sd2 = (DBX); qd = (DBY); }       \
    } else { su = nbc_s; qu = nbc_q; sd2 = nbp_s; qd = nbp_q; }                \
    if ((unsigned)j_ < 512u) {                                                 \
        float lAs = ps0, lAq = pq0;                                            \
        float m1;                                                              \
        asm("v_min3_f32 %0, %1, %2, %3" : "=v"(m1) : "v"(su), "v"(lAs), "v"(sd2)); \
        float eu, el, ed;                                                      \
        asm("v_exp_f32 %0, %1" : "=v"(eu) : "v"(m1 - su));                     \
        asm("v_exp_f32 %0, %1" : "=v"(el) : "v"(m1 - lAs));                    \
        asm("v_exp_f32 %0, %1" : "=v"(ed) : "v"(m1 - sd2));                    \
        float qA = __builtin_fmaf(qu, eu, __builtin_fmaf(lAq, el, qd * ed));   \
        float sA = cc.x + m1;                                                  \
        float m2;                                                              \
        asm("v_min3_f32 %0, %1, %2, %3" : "=v"(m2) : "v"(sA), "v"(ps1), "v"(lAs)); \
        float fu, fl, fd;                                                      \
        asm("v_exp_f32 %0, %1" : "=v"(fu) : "v"(m2 - sA));                     \
        asm("v_exp_f32 %0, %1" : "=v"(fl) : "v"(m2 - ps1));                    \
        asm("v_exp_f32 %0, %1" : "=v"(fd) : "v"(m2 - lAs));                    \
        float qB = __builtin_fmaf(qA, fu, __builtin_fmaf(pq1, fl, lAq * fd));  \
        float sB = cc.y + m2;                                                  \
        ps0 = sA; pq0 = qA; ps1 = sB; pq1 = qB;                                \
    }                                                                          \
    BS = f32x2{ps1, pq1};                                                      \
    float shs_ = __shfl_up(ps1, 1);                                            \
    float shq_ = __shfl_up(pq1, 1);                                            \
    nbp_s = nbc_s; nbp_q = nbc_q;                                              \
    nbc_s = shs_;  nbc_q = shq_;                                               \
    LOADP(REG, s_ + RING - off);                                               \
} while (0)

#define RENORM(S, Q) do {                                                      \
    int e_ = (__float_as_int(Q) >> 23) - 127;                                  \
    Q = __int_as_float(__float_as_int(Q) - (e_ << 23));                        \
    S = S - (float)e_;                                                         \
} while (0)

    for (int I = 0; I < NITER; ++I) {
        asm volatile("s_waitcnt lgkmcnt(0)" ::: "memory");
        __builtin_amdgcn_s_barrier();
        asm volatile("" ::: "memory");
        // bulk-read wave w-1's previous-chunk bottoms (broadcast b128 reads)
        const f32x4* rq = (const f32x4*)&buf[(I + 1) & 1][wm1][0];
        f32x4 c0 = rq[0], c1 = rq[1], c2 = rq[2], c3 = rq[3];
        f32x4 c4 = rq[4], c5 = rq[5], c6 = rq[6], c7 = rq[7];
        int sbase = I * KCH;
        STEP(r0, 0,  b0,  c0[0], c0[1], carry.x, carry.y);
        STEP(r1, 1,  b1,  c0[2], c0[3], c0[0], c0[1]);
        STEP(r2, 2,  b2,  c1[0], c1[1], c0[2], c0[3]);
        STEP(r3, 3,  b3,  c1[2], c1[3], c1[0], c1[1]);
        STEP(r4, 4,  b4,  c2[0], c2[1], c1[2], c1[3]);
        STEP(r5, 5,  b5,  c2[2], c2[3], c2[0], c2[1]);
        STEP(r6, 6,  b6,  c3[0], c3[1], c2[2], c2[3]);
        STEP(r7, 7,  b7,  c3[2], c3[3], c3[0], c3[1]);
        STEP(r0, 8,  b8,  c4[0], c4[1], c3[2], c3[3]);
        STEP(r1, 9,  b9,  c4[2], c4[3], c4[0], c4[1]);
        STEP(r2, 10, b10, c5[0], c5[1], c4[2], c4[3]);
        STEP(r3, 11, b11, c5[2], c5[3], c5[0], c5[1]);
        STEP(r4, 12, b12, c6[0], c6[1], c5[2], c5[3]);
        STEP(r5, 13, b13, c6[2], c6[3], c6[0], c6[1]);
        STEP(r6, 14, b14, c7[0], c7[1], c6[2], c6[3]);
        STEP(r7, 15, b15, c7[2], c7[3], c7[0], c7[1]);
        carry = f32x2{c7[2], c7[3]};
        // producer: bulk-write this chunk's 16 bottom pairs (lane 63 only)
        if (l == 63) {
            f32x2* wbp = &buf[I & 1][w][0];
            wbp[0]  = b0;  wbp[1]  = b1;  wbp[2]  = b2;  wbp[3]  = b3;
            wbp[4]  = b4;  wbp[5]  = b5;  wbp[6]  = b6;  wbp[7]  = b7;
            wbp[8]  = b8;  wbp[9]  = b9;  wbp[10] = b10; wbp[11] = b11;
            wbp[12] = b12; wbp[13] = b13; wbp[14] = b14; wbp[15] = b15;
        }
        RENORM(ps0, pq0);
        RENORM(ps1, pq1);
    }

    if (p == 255) {   // cell (511,511): single resolve
        float lg;
        asm("v_log_f32 %0, %1" : "=v"(lg) : "v"(pq1));
        part[b] = (ps1 - lg) * LN2F;
    }
#undef STEP
#undef LOADP
#undef RENORM
}

// ---------------------------------------------------------------------------
// Kernel 4: one-wave deterministic reduction. out = sum_b(R_b) / (B * N)
// ---------------------------------------------------------------------------
__global__ __launch_bounds__(64) void reduce_kernel(const float* __restrict__ part,
                                                    float* __restrict__ out) {
    int l = threadIdx.x;
    float v = part[l];
    #pragma unroll
    for (int m = 32; m >= 1; m >>= 1) v += __shfl_xor(v, m, 64);
    if (l == 0) out[0] = v / (float)(BATCH * NN);
}

// ---------------------------------------------------------------------------
extern "C" void kernel_launch(void* const* d_in, const int* in_sizes, int n_in,
                              void* d_out, int out_size, void* d_ws, size_t ws_size,
                              hipStream_t stream) {
    const float* X = (const float*)d_in[0];
    const float* Y = (const float*)d_in[1];
    float* out = (float*)d_out;

    char* ws = (char*)d_ws;
    float* CT   = (float*)ws;                                   // 64 MB
    float* x2   = (float*)(ws + (size_t)BATCH * NN * MM * 4);   // 128 KB
    float* y2   = x2 + BATCH * NN;                              // 128 KB
    float* part = y2 + BATCH * MM;                              // 256 B

    sqnorm_kernel<<<(BATCH * (NN + MM)) / 4, 256, 0, stream>>>(X, Y, x2, y2);

    dim3 g(MM / TM, NN / TM, BATCH);
    cost_kernel<<<g, 256, 0, stream>>>(X, Y, x2, y2, CT);

    sdtw_kernel<<<BATCH, 256, 0, stream>>>(CT, part);

    reduce_kernel<<<1, 64, 0, stream>>>(part, out);
}